// Round 1
// baseline (170.192 us; speedup 1.0000x reference)
//
#include <hip/hip_runtime.h>
#include <stdint.h>

typedef short short8 __attribute__((ext_vector_type(8)));
typedef float floatx4 __attribute__((ext_vector_type(4)));

#define NN 100000   // nodes
#define NE 800000   // edges
#define KF 128      // in_feat (K of node GEMM)
#define PC 256      // P columns: [0:128)=P1+b1 (src half), [128:256)=P2 (dst half)
#define BM 64       // nodes per block in node kernel
#define LDK 136     // padded LDS row stride in shorts (128 + 8): stride 68 dwords -> 2-way bank alias (free)

// fp32 -> bf16 (RNE)
__device__ __forceinline__ unsigned short f2bf(float x) {
  union { float f; unsigned u; } c; c.f = x;
  unsigned u = c.u + 0x7FFFu + ((c.u >> 16) & 1u);
  return (unsigned short)(u >> 16);
}
// bf16 (low/high half of dword) -> fp32
__device__ __forceinline__ float bfl(unsigned u) {
  union { unsigned u; float f; } c; c.u = u << 16; return c.f;
}
__device__ __forceinline__ float bfh(unsigned u) {
  union { unsigned u; float f; } c; c.u = u & 0xFFFF0000u; return c.f;
}

// ---------------------------------------------------------------------------
// Kernel 1: P[n][j] = sum_k feature[n][k] * Wcat[j][k]  (+ b1[j] for j<128)
//   Wcat[j][k] = (j<128) ? W1[j][k] : W1[j-128][128+k]
// MFMA 16x16x32 bf16. Per block: 64 nodes x 256 cols. W staged in 2 halves
// of 128 rows to keep LDS at ~52.7 KB (3 blocks/CU).
// ---------------------------------------------------------------------------
extern "C" __global__ void __launch_bounds__(256)
node_proj_kernel(const float* __restrict__ feature,
                 const float* __restrict__ W1,
                 const float* __restrict__ b1,
                 unsigned short* __restrict__ P)
{
  __shared__ unsigned short Wl[128 * LDK]; // 34816 B (one 128-row half of Wcat)
  __shared__ unsigned short Al[BM * LDK];  // 17408 B
  __shared__ float b1l[128];

  const int t = threadIdx.x;
  const int nodeBase = blockIdx.x * BM;

  // ---- stage A tile (64 nodes x 128 k, fp32 -> bf16) ----
  #pragma unroll
  for (int it = 0; it < 4; ++it) {
    int c  = t + it * 256;       // chunk of 8 elems, 0..1023
    int nl = c >> 4;             // local node 0..63
    int kc = (c & 15) << 3;      // k offset 0..120
    int node = nodeBase + nl;
    float4 f0 = make_float4(0.f, 0.f, 0.f, 0.f);
    float4 f1 = make_float4(0.f, 0.f, 0.f, 0.f);
    if (node < NN) {
      const float* fp = feature + (size_t)node * KF + kc;
      f0 = ((const float4*)fp)[0];
      f1 = ((const float4*)fp)[1];
    }
    short8 v;
    v[0] = (short)f2bf(f0.x); v[1] = (short)f2bf(f0.y);
    v[2] = (short)f2bf(f0.z); v[3] = (short)f2bf(f0.w);
    v[4] = (short)f2bf(f1.x); v[5] = (short)f2bf(f1.y);
    v[6] = (short)f2bf(f1.z); v[7] = (short)f2bf(f1.w);
    *(short8*)&Al[nl * LDK + kc] = v;
  }
  if (t < 128) b1l[t] = b1[t];

  const int wave = t >> 6;
  const int lane = t & 63;
  const int m16  = lane & 15;
  const int quad = lane >> 4;

  short8 a0, a1, a2, a3;
  bool aLoaded = false;

  for (int half = 0; half < 2; ++half) {
    // ---- stage one 128-row half of Wcat (bf16) ----
    #pragma unroll
    for (int it = 0; it < 8; ++it) {
      int c  = t + it * 256;     // 0..2047
      int jl = c >> 4;           // local row 0..127
      int kc = (c & 15) << 3;
      const float* sp = W1 + jl * 256 + half * 128 + kc;
      float4 f0 = ((const float4*)sp)[0];
      float4 f1 = ((const float4*)sp)[1];
      short8 v;
      v[0] = (short)f2bf(f0.x); v[1] = (short)f2bf(f0.y);
      v[2] = (short)f2bf(f0.z); v[3] = (short)f2bf(f0.w);
      v[4] = (short)f2bf(f1.x); v[5] = (short)f2bf(f1.y);
      v[6] = (short)f2bf(f1.z); v[7] = (short)f2bf(f1.w);
      *(short8*)&Wl[jl * LDK + kc] = v;
    }
    __syncthreads();

    if (!aLoaded) {
      const unsigned short* arow = &Al[(wave * 16 + m16) * LDK + quad * 8];
      a0 = *(const short8*)(arow + 0);
      a1 = *(const short8*)(arow + 32);
      a2 = *(const short8*)(arow + 64);
      a3 = *(const short8*)(arow + 96);
      aLoaded = true;
    }

    #pragma unroll
    for (int nt = 0; nt < 8; ++nt) {
      floatx4 acc = {0.f, 0.f, 0.f, 0.f};
      const unsigned short* wrow = &Wl[(nt * 16 + m16) * LDK + quad * 8];
      acc = __builtin_amdgcn_mfma_f32_16x16x32_bf16(a0, *(const short8*)(wrow +  0), acc, 0, 0, 0);
      acc = __builtin_amdgcn_mfma_f32_16x16x32_bf16(a1, *(const short8*)(wrow + 32), acc, 0, 0, 0);
      acc = __builtin_amdgcn_mfma_f32_16x16x32_bf16(a2, *(const short8*)(wrow + 64), acc, 0, 0, 0);
      acc = __builtin_amdgcn_mfma_f32_16x16x32_bf16(a3, *(const short8*)(wrow + 96), acc, 0, 0, 0);

      int n = half * 128 + nt * 16 + m16;
      float bias = (half == 0) ? b1l[nt * 16 + m16] : 0.f;
      #pragma unroll
      for (int r = 0; r < 4; ++r) {
        int node = nodeBase + wave * 16 + quad * 4 + r;
        if (node < NN) P[(size_t)node * PC + n] = f2bf(acc[r] + bias);
      }
    }
    __syncthreads();  // before restaging Wl for the next half
  }
}

// ---------------------------------------------------------------------------
// Kernel 2: out[e] = b2 + sum_j relu(P[src[e]][j] + P[dst[e]][128+j]) * W2[j]
// 16 lanes per edge; each lane handles 8 consecutive j via one dwordx4 per
// operand. 4-step shfl_xor reduction within the 16-lane group.
// ---------------------------------------------------------------------------
extern "C" __global__ void __launch_bounds__(256)
edge_score_kernel(const unsigned short* __restrict__ P,
                  const int* __restrict__ src,
                  const int* __restrict__ dst,
                  const float* __restrict__ W2,
                  const float* __restrict__ b2,
                  float* __restrict__ out)
{
  const int t    = threadIdx.x;
  const int lane = t & 15;
  const int g    = t >> 4;
  const int e    = blockIdx.x * 16 + g;
  if (e >= NE) return;

  const int s = src[e];
  const int d = dst[e];

  const uint4 u1 = *(const uint4*)(P + (size_t)s * PC + lane * 8);
  const uint4 u2 = *(const uint4*)(P + (size_t)d * PC + 128 + lane * 8);
  const float4 wA = *(const float4*)(W2 + lane * 8);
  const float4 wB = *(const float4*)(W2 + lane * 8 + 4);

  float acc = 0.f;
  {
    float x0 = bfl(u1.x) + bfl(u2.x); x0 = fmaxf(x0, 0.f); acc += x0 * wA.x;
    float x1 = bfh(u1.x) + bfh(u2.x); x1 = fmaxf(x1, 0.f); acc += x1 * wA.y;
  }
  {
    float x0 = bfl(u1.y) + bfl(u2.y); x0 = fmaxf(x0, 0.f); acc += x0 * wA.z;
    float x1 = bfh(u1.y) + bfh(u2.y); x1 = fmaxf(x1, 0.f); acc += x1 * wA.w;
  }
  {
    float x0 = bfl(u1.z) + bfl(u2.z); x0 = fmaxf(x0, 0.f); acc += x0 * wB.x;
    float x1 = bfh(u1.z) + bfh(u2.z); x1 = fmaxf(x1, 0.f); acc += x1 * wB.y;
  }
  {
    float x0 = bfl(u1.w) + bfl(u2.w); x0 = fmaxf(x0, 0.f); acc += x0 * wB.z;
    float x1 = bfh(u1.w) + bfh(u2.w); x1 = fmaxf(x1, 0.f); acc += x1 * wB.w;
  }

  acc += __shfl_xor(acc, 8);
  acc += __shfl_xor(acc, 4);
  acc += __shfl_xor(acc, 2);
  acc += __shfl_xor(acc, 1);

  if (lane == 0) out[e] = acc + b2[0];
}

extern "C" void kernel_launch(void* const* d_in, const int* in_sizes, int n_in,
                              void* d_out, int out_size, void* d_ws, size_t ws_size,
                              hipStream_t stream)
{
  const float* feature = (const float*)d_in[0];
  const int*   src     = (const int*)d_in[1];
  const int*   dst     = (const int*)d_in[2];
  const float* W1      = (const float*)d_in[3];
  const float* b1      = (const float*)d_in[4];
  const float* W2      = (const float*)d_in[5];
  const float* b2      = (const float*)d_in[6];
  float* out = (float*)d_out;
  unsigned short* P = (unsigned short*)d_ws;  // [NN][256] bf16, 51.2 MB

  dim3 grid1((NN + BM - 1) / BM);   // 1563 blocks
  node_proj_kernel<<<grid1, 256, 0, stream>>>(feature, W1, b1, P);

  dim3 grid2((NE + 15) / 16);       // 50000 blocks, 16 edges/block
  edge_score_kernel<<<grid2, 256, 0, stream>>>(P, src, dst, W2, b2, out);
}